// Round 1
// baseline (207.004 us; speedup 1.0000x reference)
//
#include <hip/hip_runtime.h>
#include <stdint.h>

#define IMG_H 2048
#define IMG_W 2048
#define CH_PIX (IMG_H * IMG_W)      // 4194304
#define ROWS_PER_BLOCK 8
#define MAXDET 4096
#define NBLK_A 1280                 // 5 channels * (2048/8) row tiles
#define WORDS_PER_BLOCK 256         // 16384 pixels / 64

__device__ __forceinline__ float sigmoidf_(float v) {
    // float32 1/(1+exp(-v)); expf is ~1ulp, matches np/jax rounding closely
    return 1.0f / (1.0f + expf(-v));
}

__device__ __forceinline__ float thr_load(const float* __restrict__ chan, int y, int x) {
    if ((unsigned)y >= (unsigned)IMG_H) return 0.0f;
    float a = sigmoidf_(chan[y * IMG_W + x]);
    return a > 0.3f ? a : 0.0f;
}

__global__ __launch_bounds__(256) void zero_out_k(float* __restrict__ out, int n) {
    int i = blockIdx.x * 256 + threadIdx.x;
    if (i < n) out[i] = 0.0f;
}

// Pass A: predicate masks (ordered 64-bit words) + per-block counts.
// Block = one channel x 8 full rows (16384 contiguous flat pixels).
__global__ __launch_bounds__(256) void pass_a(const float* __restrict__ feat,
                                              uint64_t* __restrict__ masks,
                                              unsigned* __restrict__ counts) {
    int blk = blockIdx.x;
    int c = blk >> 8;             // blk / 256
    int ytile = blk & 255;
    int y0 = ytile * ROWS_PER_BLOCK;
    const float* chan = feat + (size_t)c * CH_PIX;
    int t = threadIdx.x;
    int wave = t >> 6, lane = t & 63;

    __shared__ float colmax[IMG_W + 2];
    __shared__ unsigned wsum_lds[4];

    float thrprev[8], thrcur[8], thrnext[8];
#pragma unroll
    for (int j = 0; j < 8; ++j) {
        int x = j * 256 + t;
        thrprev[j] = thr_load(chan, y0 - 1, x);
        thrcur[j]  = thr_load(chan, y0,     x);
    }
    if (t == 0) { colmax[0] = 0.0f; colmax[IMG_W + 1] = 0.0f; }

    unsigned wcnt = 0;
    uint64_t base_widx = (uint64_t)blk * WORDS_PER_BLOCK;

    for (int r = 0; r < ROWS_PER_BLOCK; ++r) {
        int y = y0 + r;
#pragma unroll
        for (int j = 0; j < 8; ++j) {
            int x = j * 256 + t;
            thrnext[j] = thr_load(chan, y + 1, x);
            colmax[x + 1] = fmaxf(fmaxf(thrprev[j], thrcur[j]), thrnext[j]);
        }
        __syncthreads();
#pragma unroll
        for (int j = 0; j < 8; ++j) {
            int x = j * 256 + t;
            float pooled = fmaxf(fmaxf(colmax[x], colmax[x + 1]), colmax[x + 2]);
            bool pred = (thrcur[j] > 0.0f) && (pooled == thrcur[j]);
            uint64_t m = __ballot(pred);
            if (lane == 0) {
                masks[base_widx + (uint64_t)((r * 8 + j) * 4 + wave)] = m;
                wcnt += (unsigned)__popcll(m);
            }
        }
        __syncthreads();   // before colmax is overwritten next row
#pragma unroll
        for (int j = 0; j < 8; ++j) { thrprev[j] = thrcur[j]; thrcur[j] = thrnext[j]; }
    }
    if (lane == 0) wsum_lds[wave] = wcnt;
    __syncthreads();
    if (t == 0) counts[blk] = wsum_lds[0] + wsum_lds[1] + wsum_lds[2] + wsum_lds[3];
}

// Pass B: exclusive scan of 1280 block counts, in place.
__global__ __launch_bounds__(256) void scan_k(unsigned* __restrict__ data, int n) {
    __shared__ unsigned tmp[256];
    __shared__ unsigned carry;
    int t = threadIdx.x;
    if (t == 0) carry = 0;
    __syncthreads();
    for (int base = 0; base < n; base += 256) {
        unsigned v = (base + t < n) ? data[base + t] : 0u;
        tmp[t] = v;
        __syncthreads();
        for (int off = 1; off < 256; off <<= 1) {
            unsigned u = (t >= off) ? tmp[t - off] : 0u;
            __syncthreads();
            tmp[t] += u;
            __syncthreads();
        }
        unsigned incl = tmp[t];
        unsigned c0 = carry;
        __syncthreads();
        if (base + t < n) data[base + t] = c0 + incl - v;
        if (t == 255) carry = c0 + incl;
        __syncthreads();
    }
}

// Pass C: ordered emit of the first MAXDET detections + gather.
__global__ __launch_bounds__(256) void pass_c(const float* __restrict__ feat,
                                              const uint64_t* __restrict__ masks,
                                              const unsigned* __restrict__ offsets,
                                              float* __restrict__ out) {
    int blk = blockIdx.x;
    unsigned boff = offsets[blk];
    if (boff >= MAXDET) return;   // uniform early exit: nearly all blocks
    int t = threadIdx.x;
    uint64_t w = masks[(uint64_t)blk * WORDS_PER_BLOCK + t];
    unsigned cnt = (unsigned)__popcll(w);
    __shared__ unsigned tmp[256];
    tmp[t] = cnt;
    __syncthreads();
    for (int off = 1; off < 256; off <<= 1) {
        unsigned u = (t >= off) ? tmp[t - off] : 0u;
        __syncthreads();
        tmp[t] += u;
        __syncthreads();
    }
    unsigned rank = boff + tmp[t] - cnt;   // exclusive prefix within flat order
    while (w) {
        int b = __ffsll((unsigned long long)w) - 1;
        w &= w - 1;
        if (rank < MAXDET) {
            uint64_t p = ((uint64_t)blk * WORDS_PER_BLOCK + (uint64_t)t) * 64ull + (uint64_t)b;
            int c = (int)(p / CH_PIX);
            int rem = (int)(p % CH_PIX);
            int y = rem >> 11, x = rem & 2047;
            size_t pix = (size_t)y * IMG_W + x;
            float pm = sigmoidf_(feat[pix]);
#pragma unroll
            for (int ch = 1; ch < 5; ++ch)
                pm = fmaxf(pm, sigmoidf_(feat[(size_t)ch * CH_PIX + pix]));
            float sdv = sigmoidf_(feat[(size_t)5 * CH_PIX + pix]);
            float szv = sigmoidf_(feat[(size_t)6 * CH_PIX + pix]);
            out[rank] = pm;                                    // probs
            out[MAXDET + rank * 3 + 0] = (float)c;             // coords c
            out[MAXDET + rank * 3 + 1] = (float)y;             // coords y
            out[MAXDET + rank * 3 + 2] = (float)x;             // coords x
            out[16384 + rank] = szv;                           // size_width
            out[20480 + rank] = szv;                           // size_height
            out[24576 + rank] = sdv;                           // side_sel
        }
        rank++;
    }
}

extern "C" void kernel_launch(void* const* d_in, const int* in_sizes, int n_in,
                              void* d_out, int out_size, void* d_ws, size_t ws_size,
                              hipStream_t stream) {
    const float* feat = (const float*)d_in[0];
    float* out = (float*)d_out;
    uint64_t* masks = (uint64_t*)d_ws;                                   // 2.62 MB
    unsigned* counts = (unsigned*)((char*)d_ws + (size_t)NBLK_A * WORDS_PER_BLOCK * 8);

    zero_out_k<<<(out_size + 255) / 256, 256, 0, stream>>>(out, out_size);
    pass_a<<<NBLK_A, 256, 0, stream>>>(feat, masks, counts);
    scan_k<<<1, 256, 0, stream>>>(counts, NBLK_A);
    pass_c<<<NBLK_A, 256, 0, stream>>>(feat, masks, counts, out);
}